// Round 1
// baseline (7899.902 us; speedup 1.0000x reference)
//
#include <hip/hip_runtime.h>
#include <math.h>

// Problem constants
#define BB 64
#define TT 128
#define HH 512
#define VV 8000
#define MAXC 10

__device__ __forceinline__ float sigmoidf_(float x) { return 1.0f / (1.0f + __expf(-x)); }

// ---------------------------------------------------------------------------
// Kernel 1: x-projections (gathered-A GEMM).
//   out[r][n] = sum_k emb[idx[r]][k] * W[k][n] + bias[n],  k=0..511
// Tile 64x64, BK=16, 256 threads, 4x4 per thread.
// ---------------------------------------------------------------------------
__global__ __launch_bounds__(256) void xproj_kernel(
    const int* __restrict__ idx, const float* __restrict__ emb,
    const float* __restrict__ W, const float* __restrict__ bias,
    float* __restrict__ out, int N)
{
    __shared__ float As[16][68];
    __shared__ float Bs[16][68];
    __shared__ int rows[64];
    const int tn0 = blockIdx.x * 64, tm0 = blockIdx.y * 64;
    const int tid = threadIdx.x;
    if (tid < 64) rows[tid] = idx[tm0 + tid];
    __syncthreads();

    float acc[4][4] = {};
    const int am = tid >> 2, ak = (tid & 3) * 4;    // A load: 64 rows x 16 k
    const int bk = tid >> 4, bn = (tid & 15) * 4;   // B load: 16 k x 64 n
    const int tm = (tid >> 4) * 4, tn = (tid & 15) * 4;

    for (int k0 = 0; k0 < HH; k0 += 16) {
        const float4 av = *(const float4*)(emb + (size_t)rows[am] * HH + k0 + ak);
        As[ak + 0][am] = av.x; As[ak + 1][am] = av.y;
        As[ak + 2][am] = av.z; As[ak + 3][am] = av.w;
        *(float4*)&Bs[bk][bn] = *(const float4*)(W + (size_t)(k0 + bk) * N + tn0 + bn);
        __syncthreads();
#pragma unroll
        for (int k = 0; k < 16; ++k) {
            float a[4], b[4];
#pragma unroll
            for (int i = 0; i < 4; ++i) a[i] = As[k][tm + i];
#pragma unroll
            for (int i = 0; i < 4; ++i) b[i] = Bs[k][tn + i];
#pragma unroll
            for (int i = 0; i < 4; ++i)
#pragma unroll
                for (int j = 0; j < 4; ++j) acc[i][j] += a[i] * b[j];
        }
        __syncthreads();
    }
#pragma unroll
    for (int i = 0; i < 4; ++i)
#pragma unroll
        for (int j = 0; j < 4; ++j)
            out[(size_t)(tm0 + tm + i) * N + tn0 + tn + j] = acc[i][j] + bias[tn0 + tn + j];
}

// ---------------------------------------------------------------------------
// Kernel 2: the ACT/GRU recurrence. One block (1024 threads) per batch row.
// No grid syncs: batch rows are independent; h/acc live in LDS.
// Early-exit: once a row halts, remaining ponder iterations are exact no-ops.
// ---------------------------------------------------------------------------
__global__ __launch_bounds__(1024) void act_rnn_kernel(
    const float* __restrict__ Wg, const float* __restrict__ Wc,
    const float* __restrict__ whalt, const float* __restrict__ bhalt,
    const float* __restrict__ Xg, const float* __restrict__ Xc,
    float* __restrict__ outs, float* __restrict__ ponder_b)
{
    __shared__ float sh_h[HH], sh_acc[HH], sh_xc[HH], sh_rh[HH];
    __shared__ float sh_hnew[HH], sh_red[HH], sh_wh[HH], sh_fc[HH];
    __shared__ float sh_xg[2 * HH], sh_fg[2 * HH], sh_gpre[2 * HH], sh_part[2 * HH];
    __shared__ float s_cum, s_rem, s_nupd, s_w, s_pond;
    __shared__ int s_brk;

    const int tid = threadIdx.x;
    const int b = blockIdx.x;

    // one-time init
    sh_fg[tid] = Wg[(size_t)512 * 1024 + tid];      // flag row of W_gates
    if (tid < HH) {
        sh_fc[tid] = Wc[(size_t)512 * 512 + tid];   // flag row of W_cand
        sh_wh[tid] = whalt[tid];
        sh_h[tid] = 0.0f;
        sh_acc[tid] = 0.0f;
    }
    if (tid == 0) { s_cum = 0.f; s_rem = 0.f; s_nupd = 0.f; s_pond = 0.f; s_brk = 0; }
    const float bh = bhalt[0];
    __syncthreads();

    for (int t = 0; t < TT; ++t) {
        const int r = b * TT + t;
        sh_xg[tid] = Xg[(size_t)r * 1024 + tid];
        if (tid < HH) sh_xc[tid] = Xc[(size_t)r * HH + tid];
        __syncthreads();

        for (int i = 0; i < MAXC; ++i) {
            // phase 1: gate pre-activations gpre[j] = xg[j] (+flag row) + h . Wg_h[:,j]
            {
                const float* wcol = Wg + (size_t)513 * 1024 + tid;
                float sum = sh_xg[tid] + ((i == 0) ? sh_fg[tid] : 0.0f);
#pragma unroll 8
                for (int k = 0; k < HH; ++k) sum += sh_h[k] * wcol[(size_t)k * 1024];
                sh_gpre[tid] = sum;
            }
            __syncthreads();
            // phase 2: rh = sigmoid(r_pre) * h
            if (tid < HH) sh_rh[tid] = sigmoidf_(sh_gpre[tid]) * sh_h[tid];
            __syncthreads();
            // phase 3: candidate partials, 2 threads per output column (split K)
            {
                const int j = tid & 511, half = tid >> 9;
                const float* wcol = Wc + (size_t)(513 + half * 256) * 512 + j;
                const float* rh = sh_rh + half * 256;
                float sum = 0.0f;
#pragma unroll 8
                for (int k = 0; k < 256; ++k) sum += rh[k] * wcol[(size_t)k * 512];
                sh_part[tid] = sum;
            }
            __syncthreads();
            // phase 4: h_new = u*h + (1-u)*tanh(c_pre); prep halting dot products
            if (tid < HH) {
                float prec = sh_xc[tid] + ((i == 0) ? sh_fc[tid] : 0.0f)
                             + sh_part[tid] + sh_part[HH + tid];
                float c = tanhf(prec);
                float u = sigmoidf_(sh_gpre[HH + tid]);
                float hn = u * sh_h[tid] + (1.0f - u) * c;
                sh_hnew[tid] = hn;
                sh_red[tid] = hn * sh_wh[tid];
            }
            __syncthreads();
            // phase 5: reduce halting logit; ACT scalar bookkeeping on lane 0
            if (tid < 64) {
                float s = 0.0f;
#pragma unroll
                for (int m = 0; m < 8; ++m) s += sh_red[tid + 64 * m];
#pragma unroll
                for (int off = 32; off > 0; off >>= 1) s += __shfl_down(s, off, 64);
                if (tid == 0) {
                    float p = sigmoidf_(s + bh);
                    float cum = s_cum;
                    // `still` is true at every executed iteration (we break on halt)
                    bool halts = (cum + p >= 0.99f) || (i == MAXC - 1);
                    s_w = halts ? (1.0f - cum) : p;
                    if (halts) s_rem = 1.0f - cum;
                    s_nupd += 1.0f;
                    s_cum = cum + p;
                    s_brk = halts ? 1 : 0;
                }
            }
            __syncthreads();
            // phase 6: accumulate weighted output, carry h
            if (tid < HH) {
                sh_acc[tid] += s_w * sh_hnew[tid];
                sh_h[tid] = sh_hnew[tid];
            }
            __syncthreads();
            if (s_brk) break;
        }

        // timestep epilogue: out = acc; NEXT-TIMESTEP STATE IS acc (not h)
        if (tid < HH) {
            float a = sh_acc[tid];
            outs[(size_t)r * HH + tid] = a;
            sh_h[tid] = a;
            sh_acc[tid] = 0.0f;
        }
        if (tid == 0) {
            s_pond += s_nupd + s_rem;
            s_cum = 0.f; s_rem = 0.f; s_nupd = 0.f; s_brk = 0;
        }
        __syncthreads();
    }
    if (tid == 0) ponder_b[b] = s_pond;
}

// ---------------------------------------------------------------------------
// Kernel 3: logits = outs @ softmax_w^T + softmax_b. Tile 64x64, BK=16.
// ---------------------------------------------------------------------------
__global__ __launch_bounds__(256) void logits_kernel(
    const float* __restrict__ Amat, const float* __restrict__ sw,
    const float* __restrict__ sb, float* __restrict__ out)
{
    __shared__ float As[16][68];
    __shared__ float Bs[16][68];
    const int tn0 = blockIdx.x * 64, tm0 = blockIdx.y * 64;
    const int tid = threadIdx.x;

    float acc[4][4] = {};
    const int am = tid >> 2, ak = (tid & 3) * 4;     // A: 64 rows x 16 k
    const int bn_ = tid >> 2, bkq = (tid & 3) * 4;   // B: 64 n-rows x 4 consecutive k
    const int tm = (tid >> 4) * 4, tn = (tid & 15) * 4;

    for (int k0 = 0; k0 < HH; k0 += 16) {
        const float4 av = *(const float4*)(Amat + (size_t)(tm0 + am) * HH + k0 + ak);
        As[ak + 0][am] = av.x; As[ak + 1][am] = av.y;
        As[ak + 2][am] = av.z; As[ak + 3][am] = av.w;
        const float4 bv = *(const float4*)(sw + (size_t)(tn0 + bn_) * HH + k0 + bkq);
        Bs[bkq + 0][bn_] = bv.x; Bs[bkq + 1][bn_] = bv.y;
        Bs[bkq + 2][bn_] = bv.z; Bs[bkq + 3][bn_] = bv.w;
        __syncthreads();
#pragma unroll
        for (int k = 0; k < 16; ++k) {
            float a[4], b[4];
#pragma unroll
            for (int i = 0; i < 4; ++i) a[i] = As[k][tm + i];
#pragma unroll
            for (int i = 0; i < 4; ++i) b[i] = Bs[k][tn + i];
#pragma unroll
            for (int i = 0; i < 4; ++i)
#pragma unroll
                for (int j = 0; j < 4; ++j) acc[i][j] += a[i] * b[j];
        }
        __syncthreads();
    }
#pragma unroll
    for (int i = 0; i < 4; ++i)
#pragma unroll
        for (int j = 0; j < 4; ++j)
            out[(size_t)(tm0 + tm + i) * VV + tn0 + tn + j] = acc[i][j] + sb[tn0 + tn + j];
}

// ---------------------------------------------------------------------------
// Kernel 4: ponder cost = 0.01 * mean_b(ponder_b)
// ---------------------------------------------------------------------------
__global__ void ponder_kernel(const float* __restrict__ pb, float* __restrict__ out,
                              unsigned long long off)
{
    const int lane = threadIdx.x;
    float v = pb[lane];
#pragma unroll
    for (int o = 32; o > 0; o >>= 1) v += __shfl_down(v, o, 64);
    if (lane == 0) out[off] = 0.01f * (v * (1.0f / 64.0f));
}

// ---------------------------------------------------------------------------
extern "C" void kernel_launch(void* const* d_in, const int* in_sizes, int n_in,
                              void* d_out, int out_size, void* d_ws, size_t ws_size,
                              hipStream_t stream)
{
    const int*   idx = (const int*)d_in[0];
    const float* emb = (const float*)d_in[1];
    const float* Wg  = (const float*)d_in[2];
    const float* bg  = (const float*)d_in[3];
    const float* Wc  = (const float*)d_in[4];
    const float* bc  = (const float*)d_in[5];
    const float* wh  = (const float*)d_in[6];
    const float* bh  = (const float*)d_in[7];
    const float* sw  = (const float*)d_in[8];
    const float* sb  = (const float*)d_in[9];
    float* out = (float*)d_out;

    float* ws   = (float*)d_ws;
    float* Xg   = ws;                              // [8192][1024]
    float* Xc   = Xg + (size_t)8192 * 1024;        // [8192][512]
    float* outs = Xc + (size_t)8192 * 512;         // [8192][512]
    float* pb   = outs + (size_t)8192 * 512;       // [64]

    xproj_kernel<<<dim3(16, 128), 256, 0, stream>>>(idx, emb, Wg, bg, Xg, 1024);
    xproj_kernel<<<dim3(8, 128), 256, 0, stream>>>(idx, emb, Wc, bc, Xc, 512);
    act_rnn_kernel<<<BB, 1024, 0, stream>>>(Wg, Wc, wh, bh, Xg, Xc, outs, pb);
    logits_kernel<<<dim3(VV / 64, 128), 256, 0, stream>>>(outs, sw, sb, out);
    ponder_kernel<<<1, 64, 0, stream>>>(pb, out, (unsigned long long)8192 * VV);
}

// Round 2
// 5717.868 us; speedup vs baseline: 1.3816x; 1.3816x over previous
//
#include <hip/hip_runtime.h>
#include <math.h>

#define BB 64
#define TT 128
#define HH 512
#define VV 8000
#define MAXC 10
#define GBLK 32          // recurrent kernel blocks (barrier participants)
#define RTHREADS 512

typedef short short8 __attribute__((ext_vector_type(8)));
typedef float floatx4 __attribute__((ext_vector_type(4)));

__device__ __forceinline__ float sigmoidf_(float x) { return 1.0f / (1.0f + __expf(-x)); }
__device__ __forceinline__ unsigned short f2bf(float x) {
    unsigned int u = __float_as_uint(x);
    unsigned int r = u + 0x7FFFu + ((u >> 16) & 1u);
    return (unsigned short)(r >> 16);
}
__device__ __forceinline__ float bf2f(unsigned short h) {
    return __uint_as_float(((unsigned int)h) << 16);
}

// global barrier: fresh counter slot per use (no reset races); counters zeroed
// by hipMemsetAsync before launch. All GBLK blocks co-resident (32 << 256 CUs).
__device__ __forceinline__ void gbar(unsigned int* cnt, int s) {
    __syncthreads();
    if (threadIdx.x == 0) {
        __threadfence();  // release: drain + L2 writeback (agent scope)
        unsigned int* c = cnt + s;
        __hip_atomic_fetch_add(c, 1u, __ATOMIC_RELEASE, __HIP_MEMORY_SCOPE_AGENT);
        while (__hip_atomic_load(c, __ATOMIC_ACQUIRE, __HIP_MEMORY_SCOPE_AGENT) < GBLK) {}
        __threadfence();  // acquire: invalidate caches
    }
    __syncthreads();
}

// ---------------------------------------------------------------------------
// Kernel 0: transpose+bf16-convert the hidden-state parts of W_gates/W_cand:
//   WgT[n][k] = Wg[513+k][n]  (n<1024, k<512);  WcT[n][k] = Wc[513+k][n]
// ---------------------------------------------------------------------------
__global__ __launch_bounds__(256) void transpose_w(
    const float* __restrict__ Wg, const float* __restrict__ Wc,
    unsigned short* __restrict__ WgT, unsigned short* __restrict__ WcT)
{
    __shared__ float tile[64][65];
    int bid = blockIdx.x;
    const float* src; unsigned short* dst; int N, n0, k0;
    if (bid < 128) { src = Wg + (size_t)513 * 1024; dst = WgT; N = 1024;
                     n0 = (bid & 15) * 64; k0 = (bid >> 4) * 64; }
    else { bid -= 128; src = Wc + (size_t)513 * 512; dst = WcT; N = 512;
           n0 = (bid & 7) * 64; k0 = (bid >> 3) * 64; }
    const int tid = threadIdx.x;
    const int nn = tid & 63, kb = tid >> 6;
#pragma unroll
    for (int p = 0; p < 16; ++p) {
        int kk = kb + p * 4;
        tile[kk][nn] = src[(size_t)(k0 + kk) * N + n0 + nn];
    }
    __syncthreads();
    const int kk2 = tid & 63;
#pragma unroll
    for (int p = 0; p < 16; ++p) {
        int nn2 = kb + p * 4;
        dst[(size_t)(n0 + nn2) * 512 + k0 + kk2] = f2bf(tile[kk2][nn2]);
    }
}

// ---------------------------------------------------------------------------
// Kernel 1: x-projections (gathered-A GEMM), output TRANSPOSED to [t][b][N]
// (t-major so the recurrent kernel reads contiguous rows). Optional bf16 out.
// ---------------------------------------------------------------------------
__global__ __launch_bounds__(256) void xproj_kernel(
    const int* __restrict__ idx, const float* __restrict__ emb,
    const float* __restrict__ W, const float* __restrict__ bias,
    float* __restrict__ outf, unsigned short* __restrict__ outb, int N)
{
    __shared__ float As[16][68];
    __shared__ float Bs[16][68];
    __shared__ int rows[64];
    const int tn0 = blockIdx.x * 64, tm0 = blockIdx.y * 64;
    const int tid = threadIdx.x;
    if (tid < 64) rows[tid] = idx[tm0 + tid];
    __syncthreads();

    float acc[4][4] = {};
    const int am = tid >> 2, ak = (tid & 3) * 4;
    const int bk = tid >> 4, bn = (tid & 15) * 4;
    const int tm = (tid >> 4) * 4, tn = (tid & 15) * 4;

    for (int k0 = 0; k0 < HH; k0 += 16) {
        const float4 av = *(const float4*)(emb + (size_t)rows[am] * HH + k0 + ak);
        As[ak + 0][am] = av.x; As[ak + 1][am] = av.y;
        As[ak + 2][am] = av.z; As[ak + 3][am] = av.w;
        *(float4*)&Bs[bk][bn] = *(const float4*)(W + (size_t)(k0 + bk) * N + tn0 + bn);
        __syncthreads();
#pragma unroll
        for (int k = 0; k < 16; ++k) {
            float a[4], b[4];
#pragma unroll
            for (int i = 0; i < 4; ++i) a[i] = As[k][tm + i];
#pragma unroll
            for (int i = 0; i < 4; ++i) b[i] = Bs[k][tn + i];
#pragma unroll
            for (int i = 0; i < 4; ++i)
#pragma unroll
                for (int j = 0; j < 4; ++j) acc[i][j] += a[i] * b[j];
        }
        __syncthreads();
    }
#pragma unroll
    for (int i = 0; i < 4; ++i) {
        int r = tm0 + tm + i;
        size_t orow = (size_t)((r % TT) * 64 + r / TT);   // [t][b]
#pragma unroll
        for (int j = 0; j < 4; ++j) {
            float v = acc[i][j] + bias[tn0 + tn + j];
            if (outb) outb[orow * N + tn0 + tn + j] = f2bf(v);
            else      outf[orow * N + tn0 + tn + j] = v;
        }
    }
}

// ---------------------------------------------------------------------------
// Kernel 2: batched ACT/GRU recurrence. 32 blocks x 512 threads cooperate on
// all 64 batch rows; block g owns hidden cols [16g,16g+16). Weights + full H
// copy LDS-resident (bf16); MFMA GEMMs; custom global barriers between the
// column-parallel stages. All blocks compute identical scalar ACT state from
// identical global data => identical barrier counts (no deadlock).
// ---------------------------------------------------------------------------
__global__ __launch_bounds__(RTHREADS) void act_rnn_batched(
    const unsigned short* __restrict__ WgT, const unsigned short* __restrict__ WcT,
    const float* __restrict__ Wg, const float* __restrict__ Wc,
    const float* __restrict__ whalt, const float* __restrict__ bhalt,
    const unsigned short* __restrict__ Xg, const float* __restrict__ Xc,
    float* __restrict__ outs, float* __restrict__ ponder_b,
    unsigned short* __restrict__ RHX, unsigned short* __restrict__ HNX,
    unsigned short* __restrict__ AccX, float* __restrict__ Pp,
    unsigned int* __restrict__ cnt)
{
    __shared__ unsigned short Hs[64][520];    // full h, bf16, padded (+8) for banks
    __shared__ unsigned short Wgl[32][520];   // rows 0-15: r-cols, 16-31: u-cols (W^T)
    __shared__ unsigned short Wcl[16][520];   // cand cols (W^T)
    __shared__ float u_l[64][16];
    __shared__ float pl[64][17];
    __shared__ float w_s[64], cum_s[64], rem_s[64], nupd_s[64], pond_s[64];
    __shared__ int still_s[64];
    __shared__ int allh_s;
    __shared__ float fg_l[32], fc_l[16], wh_l[16];

    const int tid = threadIdx.x;
    const int g = blockIdx.x;
    const int wv = tid >> 6, lane = tid & 63, l15 = lane & 15, quad = lane >> 4;
    const int mt = wv & 3, nt = wv >> 2;

    // ---- one-time init: weight slices -> LDS
    {
        int row = tid >> 4;                 // 0..31
        int c0 = (tid & 15) * 32;           // shorts
        int src_n = (row < 16) ? (16 * g + row) : (512 + 16 * g + (row - 16));
        const unsigned short* s = WgT + (size_t)src_n * 512 + c0;
        unsigned short* d = &Wgl[row][c0];
#pragma unroll
        for (int q = 0; q < 4; ++q) ((uint4*)d)[q] = ((const uint4*)s)[q];
    }
    if (tid < 256) {
        int row = tid >> 4;                 // 0..15
        int c0 = (tid & 15) * 32;
        const unsigned short* s = WcT + (size_t)(16 * g + row) * 512 + c0;
        unsigned short* d = &Wcl[row][c0];
#pragma unroll
        for (int q = 0; q < 4; ++q) ((uint4*)d)[q] = ((const uint4*)s)[q];
    }
    if (tid < 32) fg_l[tid] = Wg[(size_t)512 * 1024 +
                                 ((tid < 16) ? (16 * g + tid) : (512 + 16 * g + tid - 16))];
    if (tid < 16) { fc_l[tid] = Wc[(size_t)512 * 512 + 16 * g + tid];
                    wh_l[tid] = whalt[16 * g + tid]; }
    for (int x = tid; x < 64 * 520; x += RTHREADS) ((unsigned short*)Hs)[x] = 0;
    if (tid < 64) { cum_s[tid] = 0; rem_s[tid] = 0; nupd_s[tid] = 0; pond_s[tid] = 0; }
    const float bh = bhalt[0];
    __syncthreads();

    int seq = 0;
    floatx4 accr = {0, 0, 0, 0};            // persistent weighted-output acc (waves 0-3)
    float hn[4] = {0, 0, 0, 0};

    for (int t = 0; t < TT; ++t) {
        for (int i = 0; i < MAXC; ++i) {
            // ---- stage A: gates GEMM  C[64][32] = Hs @ Wg_slice
            floatx4 acg = {0, 0, 0, 0};
            const int arow = mt * 16 + l15;
            const int brow = nt * 16 + l15;
#pragma unroll
            for (int kk = 0; kk < 16; ++kk) {
                short8 a = *(const short8*)&Hs[arow][kk * 32 + quad * 8];
                short8 b = *(const short8*)&Wgl[brow][kk * 32 + quad * 8];
                acg = __builtin_amdgcn_mfma_f32_16x16x32_bf16(a, b, acg, 0, 0, 0);
            }
            const int gcol = (nt == 0) ? (16 * g + l15) : (512 + 16 * g + l15);
#pragma unroll
            for (int e = 0; e < 4; ++e) {
                int m = mt * 16 + quad * 4 + e;
                float pre = acg[e] + bf2f(Xg[(size_t)(t * 64 + m) * 1024 + gcol])
                            + ((i == 0) ? fg_l[nt * 16 + l15] : 0.0f);
                float s = sigmoidf_(pre);
                if (nt == 0) {
                    float rh = s * bf2f(Hs[m][16 * g + l15]);
                    RHX[(size_t)m * 512 + 16 * g + l15] = f2bf(rh);
                } else {
                    u_l[m][l15] = s;
                }
            }
            gbar(cnt, seq++);               // rh slices complete device-wide

            // ---- stage B: cand GEMM  C2[64][16] = RH @ Wc_slice  (waves 0-3)
            if (wv < 4) {
                short8 af[16];
#pragma unroll
                for (int kk = 0; kk < 16; ++kk)
                    af[kk] = *(const short8*)&RHX[(size_t)(mt * 16 + l15) * 512 + kk * 32 + quad * 8];
                floatx4 ac2 = {0, 0, 0, 0};
#pragma unroll
                for (int kk = 0; kk < 16; ++kk) {
                    short8 b = *(const short8*)&Wcl[l15][kk * 32 + quad * 8];
                    ac2 = __builtin_amdgcn_mfma_f32_16x16x32_bf16(af[kk], b, ac2, 0, 0, 0);
                }
#pragma unroll
                for (int e = 0; e < 4; ++e) {
                    int m = mt * 16 + quad * 4 + e;
                    int j = 16 * g + l15;
                    float pre = ac2[e] + Xc[(size_t)(t * 64 + m) * 512 + j]
                                + ((i == 0) ? fc_l[l15] : 0.0f);
                    float c = tanhf(pre);
                    float u = u_l[m][l15];
                    float h = bf2f(Hs[m][j]);
                    hn[e] = u * h + (1.0f - u) * c;
                    HNX[(size_t)m * 512 + j] = f2bf(hn[e]);
                    pl[m][l15] = hn[e] * wh_l[l15];
                }
            }
            __syncthreads();
            if (tid < 64) {
                float s = 0.0f;
#pragma unroll
                for (int j = 0; j < 16; ++j) s += pl[tid][j];
                Pp[g * 64 + tid] = s;       // halting-logit partial, one writer per slot
            }
            gbar(cnt, seq++);               // h_new + partials complete device-wide

            // ---- stage C: ACT bookkeeping (redundant, deterministic) + refresh
            if (tid < 64) {
                float logit = bh;
                for (int gg = 0; gg < GBLK; ++gg) logit += Pp[gg * 64 + tid];
                float p = sigmoidf_(logit);
                float cum = cum_s[tid];
                bool still = cum < 0.99f;
                bool halts = still && ((cum + p >= 0.99f) || (i == MAXC - 1));
                w_s[tid] = still ? (halts ? (1.0f - cum) : p) : 0.0f;
                still_s[tid] = still ? 1 : 0;
                if (halts) rem_s[tid] = 1.0f - cum;
                if (still) { nupd_s[tid] += 1.0f; cum_s[tid] = cum + p; }
                unsigned long long act = __ballot(still && !halts);
                if (tid == 0) allh_s = (act == 0ull) ? 1 : 0;
            }
            __syncthreads();
            if (wv < 4) {
#pragma unroll
                for (int e = 0; e < 4; ++e) {
                    int m = mt * 16 + quad * 4 + e;
                    accr[e] += w_s[m] * hn[e];
                }
            }
            {   // Hs := still ? h_new : Hs   (full copy, 128 B/thread)
                int row = tid >> 3;
                int c0 = (tid & 7) * 64;
                if (still_s[row]) {
                    const uint4* s = (const uint4*)&HNX[(size_t)row * 512 + c0];
                    uint4* d = (uint4*)&Hs[row][c0];
#pragma unroll
                    for (int q = 0; q < 8; ++q) d[q] = s[q];
                }
            }
            __syncthreads();
            if (allh_s) break;              // uniform across blocks
        }

        // ---- timestep epilogue: output = acc; NEXT-STEP STATE = acc
        if (wv < 4) {
#pragma unroll
            for (int e = 0; e < 4; ++e) {
                int m = mt * 16 + quad * 4 + e;
                int j = 16 * g + l15;
                outs[(size_t)(m * TT + t) * 512 + j] = accr[e];
                AccX[(size_t)m * 512 + j] = f2bf(accr[e]);
                accr[e] = 0.0f;
            }
        }
        if (tid < 64) {
            pond_s[tid] += nupd_s[tid] + rem_s[tid];
            cum_s[tid] = 0; rem_s[tid] = 0; nupd_s[tid] = 0;
        }
        gbar(cnt, seq++);                   // acc slices complete device-wide
        {
            int row = tid >> 3;
            int c0 = (tid & 7) * 64;
            const uint4* s = (const uint4*)&AccX[(size_t)row * 512 + c0];
            uint4* d = (uint4*)&Hs[row][c0];
#pragma unroll
            for (int q = 0; q < 8; ++q) d[q] = s[q];
        }
        __syncthreads();
    }
    if (g == 0 && tid < 64) ponder_b[tid] = pond_s[tid];
}

// ---------------------------------------------------------------------------
// Kernel 3: logits = outs @ softmax_w^T + softmax_b. Tile 64x64, BK=16.
// ---------------------------------------------------------------------------
__global__ __launch_bounds__(256) void logits_kernel(
    const float* __restrict__ Amat, const float* __restrict__ sw,
    const float* __restrict__ sb, float* __restrict__ out)
{
    __shared__ float As[16][68];
    __shared__ float Bs[16][68];
    const int tn0 = blockIdx.x * 64, tm0 = blockIdx.y * 64;
    const int tid = threadIdx.x;

    float acc[4][4] = {};
    const int am = tid >> 2, ak = (tid & 3) * 4;
    const int bn_ = tid >> 2, bkq = (tid & 3) * 4;
    const int tm = (tid >> 4) * 4, tn = (tid & 15) * 4;

    for (int k0 = 0; k0 < HH; k0 += 16) {
        const float4 av = *(const float4*)(Amat + (size_t)(tm0 + am) * HH + k0 + ak);
        As[ak + 0][am] = av.x; As[ak + 1][am] = av.y;
        As[ak + 2][am] = av.z; As[ak + 3][am] = av.w;
        const float4 bv = *(const float4*)(sw + (size_t)(tn0 + bn_) * HH + k0 + bkq);
        Bs[bkq + 0][bn_] = bv.x; Bs[bkq + 1][bn_] = bv.y;
        Bs[bkq + 2][bn_] = bv.z; Bs[bkq + 3][bn_] = bv.w;
        __syncthreads();
#pragma unroll
        for (int k = 0; k < 16; ++k) {
            float a[4], b[4];
#pragma unroll
            for (int i = 0; i < 4; ++i) a[i] = As[k][tm + i];
#pragma unroll
            for (int i = 0; i < 4; ++i) b[i] = Bs[k][tn + i];
#pragma unroll
            for (int i = 0; i < 4; ++i)
#pragma unroll
                for (int j = 0; j < 4; ++j) acc[i][j] += a[i] * b[j];
        }
        __syncthreads();
    }
#pragma unroll
    for (int i = 0; i < 4; ++i)
#pragma unroll
        for (int j = 0; j < 4; ++j)
            out[(size_t)(tm0 + tm + i) * VV + tn0 + tn + j] = acc[i][j] + sb[tn0 + tn + j];
}

// ---------------------------------------------------------------------------
// Kernel 4: ponder cost = 0.01 * mean_b(ponder_b)
// ---------------------------------------------------------------------------
__global__ void ponder_kernel(const float* __restrict__ pb, float* __restrict__ out,
                              unsigned long long off)
{
    const int lane = threadIdx.x;
    float v = pb[lane];
#pragma unroll
    for (int o = 32; o > 0; o >>= 1) v += __shfl_down(v, o, 64);
    if (lane == 0) out[off] = 0.01f * (v * (1.0f / 64.0f));
}

// ---------------------------------------------------------------------------
extern "C" void kernel_launch(void* const* d_in, const int* in_sizes, int n_in,
                              void* d_out, int out_size, void* d_ws, size_t ws_size,
                              hipStream_t stream)
{
    const int*   idx = (const int*)d_in[0];
    const float* emb = (const float*)d_in[1];
    const float* Wg  = (const float*)d_in[2];
    const float* bg  = (const float*)d_in[3];
    const float* Wc  = (const float*)d_in[4];
    const float* bc  = (const float*)d_in[5];
    const float* wh  = (const float*)d_in[6];
    const float* bh  = (const float*)d_in[7];
    const float* sw  = (const float*)d_in[8];
    const float* sb  = (const float*)d_in[9];
    float* out = (float*)d_out;

    // workspace layout (16-B aligned segments), ~50 MB total
    float* ws   = (float*)d_ws;
    float* Xc   = ws;                                   // [128*64][512] f32
    float* outs = Xc + (size_t)8192 * 512;              // [B*T][512] f32
    float* pb   = outs + (size_t)8192 * 512;            // [64]
    float* Pp   = pb + 64;                              // [32][64]
    unsigned int* cnt = (unsigned int*)(Pp + 2048);     // [4096] barrier slots
    unsigned short* Xg  = (unsigned short*)(cnt + 4096);// [128*64][1024] bf16
    unsigned short* WgT = Xg + (size_t)8192 * 1024;     // [1024][512] bf16
    unsigned short* WcT = WgT + (size_t)1024 * 512;     // [512][512]  bf16
    unsigned short* RHX = WcT + (size_t)512 * 512;      // [64][512]   bf16
    unsigned short* HNX = RHX + (size_t)64 * 512;
    unsigned short* AccX = HNX + (size_t)64 * 512;

    hipMemsetAsync(cnt, 0, 4096 * sizeof(unsigned int), stream);
    transpose_w<<<192, 256, 0, stream>>>(Wg, Wc, WgT, WcT);
    xproj_kernel<<<dim3(16, 128), 256, 0, stream>>>(idx, emb, Wg, bg, nullptr, Xg, 1024);
    xproj_kernel<<<dim3(8, 128), 256, 0, stream>>>(idx, emb, Wc, bc, Xc, nullptr, 512);
    act_rnn_batched<<<GBLK, RTHREADS, 0, stream>>>(WgT, WcT, Wg, Wc, wh, bh, Xg, Xc,
                                                   outs, pb, RHX, HNX, AccX, Pp, cnt);
    logits_kernel<<<dim3(VV / 64, 128), 256, 0, stream>>>(outs, sw, sb, out);
    ponder_kernel<<<1, 64, 0, stream>>>(pb, out, (unsigned long long)8192 * VV);
}

// Round 3
// 4743.341 us; speedup vs baseline: 1.6655x; 1.2055x over previous
//
#include <hip/hip_runtime.h>
#include <math.h>

#define BB 64
#define TT 128
#define HH 512
#define VV 8000
#define MAXC 10
#define GBLK 32          // recurrent kernel blocks (barrier participants)
#define RTHREADS 512

typedef short short8 __attribute__((ext_vector_type(8)));
typedef float floatx4 __attribute__((ext_vector_type(4)));
typedef unsigned long long u64;

__device__ __forceinline__ float sigmoidf_(float x) { return 1.0f / (1.0f + __expf(-x)); }
__device__ __forceinline__ unsigned short f2bf(float x) {
    unsigned int u = __float_as_uint(x);
    unsigned int r = u + 0x7FFFu + ((u >> 16) & 1u);
    return (unsigned short)(r >> 16);
}
__device__ __forceinline__ float bf2f(unsigned short h) {
    return __uint_as_float(((unsigned int)h) << 16);
}

// Fine-grained coherent (sc0 sc1) accesses — bypass non-coherent L1/L2, no flushes.
__device__ __forceinline__ u64 ald8(const unsigned short* p) {
    return __hip_atomic_load((const u64*)p, __ATOMIC_RELAXED, __HIP_MEMORY_SCOPE_AGENT);
}
__device__ __forceinline__ void ast8(unsigned short* p, u64 v) {
    __hip_atomic_store((u64*)p, v, __ATOMIC_RELAXED, __HIP_MEMORY_SCOPE_AGENT);
}
__device__ __forceinline__ short8 ald16(const unsigned short* p) {
    union { short8 v; u64 q[2]; } u;
    u.q[0] = ald8(p); u.q[1] = ald8(p + 4);
    return u.v;
}

// Flag-array global barrier: no contention, no cache flushes.
// __syncthreads() drains vmcnt(0) (HIP semantics) => prior sc1 stores complete
// device-wide before the flag store. Poll: one coalesced 32-lane load per round.
__device__ __forceinline__ void xbar(unsigned int* flags, unsigned int seq) {
    __syncthreads();
    if (threadIdx.x == 0)
        __hip_atomic_store(flags + blockIdx.x, seq, __ATOMIC_RELAXED, __HIP_MEMORY_SCOPE_AGENT);
    if (threadIdx.x < 64) {
        unsigned int f = seq;
        do {
            if (threadIdx.x < GBLK)
                f = __hip_atomic_load(flags + threadIdx.x, __ATOMIC_RELAXED,
                                      __HIP_MEMORY_SCOPE_AGENT);
        } while (__ballot(f < seq) != 0ull);
    }
    __syncthreads();
}

// ---------------------------------------------------------------------------
// Kernel 0: transpose+bf16-convert hidden-state parts of W_gates/W_cand.
// ---------------------------------------------------------------------------
__global__ __launch_bounds__(256) void transpose_w(
    const float* __restrict__ Wg, const float* __restrict__ Wc,
    unsigned short* __restrict__ WgT, unsigned short* __restrict__ WcT)
{
    __shared__ float tile[64][65];
    int bid = blockIdx.x;
    const float* src; unsigned short* dst; int N, n0, k0;
    if (bid < 128) { src = Wg + (size_t)513 * 1024; dst = WgT; N = 1024;
                     n0 = (bid & 15) * 64; k0 = (bid >> 4) * 64; }
    else { bid -= 128; src = Wc + (size_t)513 * 512; dst = WcT; N = 512;
           n0 = (bid & 7) * 64; k0 = (bid >> 3) * 64; }
    const int tid = threadIdx.x;
    const int nn = tid & 63, kb = tid >> 6;
#pragma unroll
    for (int p = 0; p < 16; ++p) {
        int kk = kb + p * 4;
        tile[kk][nn] = src[(size_t)(k0 + kk) * N + n0 + nn];
    }
    __syncthreads();
    const int kk2 = tid & 63;
#pragma unroll
    for (int p = 0; p < 16; ++p) {
        int nn2 = kb + p * 4;
        dst[(size_t)(n0 + nn2) * 512 + k0 + kk2] = f2bf(tile[kk2][nn2]);
    }
}

// ---------------------------------------------------------------------------
// Kernel 1: x-projections (gathered-A GEMM), output transposed to [t][b][N].
// ---------------------------------------------------------------------------
__global__ __launch_bounds__(256) void xproj_kernel(
    const int* __restrict__ idx, const float* __restrict__ emb,
    const float* __restrict__ W, const float* __restrict__ bias,
    float* __restrict__ outf, unsigned short* __restrict__ outb, int N)
{
    __shared__ float As[16][68];
    __shared__ float Bs[16][68];
    __shared__ int rows[64];
    const int tn0 = blockIdx.x * 64, tm0 = blockIdx.y * 64;
    const int tid = threadIdx.x;
    if (tid < 64) rows[tid] = idx[tm0 + tid];
    __syncthreads();

    float acc[4][4] = {};
    const int am = tid >> 2, ak = (tid & 3) * 4;
    const int bk = tid >> 4, bn = (tid & 15) * 4;
    const int tm = (tid >> 4) * 4, tn = (tid & 15) * 4;

    for (int k0 = 0; k0 < HH; k0 += 16) {
        const float4 av = *(const float4*)(emb + (size_t)rows[am] * HH + k0 + ak);
        As[ak + 0][am] = av.x; As[ak + 1][am] = av.y;
        As[ak + 2][am] = av.z; As[ak + 3][am] = av.w;
        *(float4*)&Bs[bk][bn] = *(const float4*)(W + (size_t)(k0 + bk) * N + tn0 + bn);
        __syncthreads();
#pragma unroll
        for (int k = 0; k < 16; ++k) {
            float a[4], b[4];
#pragma unroll
            for (int i = 0; i < 4; ++i) a[i] = As[k][tm + i];
#pragma unroll
            for (int i = 0; i < 4; ++i) b[i] = Bs[k][tn + i];
#pragma unroll
            for (int i = 0; i < 4; ++i)
#pragma unroll
                for (int j = 0; j < 4; ++j) acc[i][j] += a[i] * b[j];
        }
        __syncthreads();
    }
#pragma unroll
    for (int i = 0; i < 4; ++i) {
        int r = tm0 + tm + i;
        size_t orow = (size_t)((r % TT) * 64 + r / TT);   // [t][b]
#pragma unroll
        for (int j = 0; j < 4; ++j) {
            float v = acc[i][j] + bias[tn0 + tn + j];
            if (outb) outb[orow * N + tn0 + tn + j] = f2bf(v);
            else      outf[orow * N + tn0 + tn + j] = v;
        }
    }
}

// ---------------------------------------------------------------------------
// Kernel 2: batched ACT/GRU recurrence. 32 blocks x 512 threads, block g owns
// hidden cols [16g,16g+16). All cross-block traffic via sc1 coherent accesses.
// ---------------------------------------------------------------------------
__global__ __launch_bounds__(RTHREADS) void act_rnn_batched(
    const unsigned short* __restrict__ WgT, const unsigned short* __restrict__ WcT,
    const float* __restrict__ Wg, const float* __restrict__ Wc,
    const float* __restrict__ whalt, const float* __restrict__ bhalt,
    const unsigned short* __restrict__ Xg, const float* __restrict__ Xc,
    unsigned short* __restrict__ outsb, float* __restrict__ ponder_b,
    unsigned short* __restrict__ RHX, unsigned short* __restrict__ HNX,
    unsigned short* __restrict__ AccX, float* __restrict__ Pp,
    unsigned int* __restrict__ flags)
{
    __shared__ unsigned short Hs[64][520];    // full h (bf16), +8 pad
    __shared__ unsigned short Wgl[32][520];   // rows 0-15 r-cols, 16-31 u-cols (W^T)
    __shared__ unsigned short Wcl[16][520];   // cand cols (W^T)
    __shared__ unsigned short xg_l[64][32];   // per-timestep Xg slice (bf16 raw)
    __shared__ float xc_l[64][16];            // per-timestep Xc slice
    __shared__ float u_l[64][16];
    __shared__ float rh_l[64][16];            // also reused for acc in epilogue
    __shared__ float hn_l[64][16];
    __shared__ float pl[64][17];
    __shared__ float w_s[64], cum_s[64], rem_s[64], nupd_s[64], pond_s[64];
    __shared__ int still_s[64];
    __shared__ int allh_s;
    __shared__ float fg_l[32], fc_l[16], wh_l[16];

    const int tid = threadIdx.x;
    const int g = blockIdx.x;
    const int wv = tid >> 6, lane = tid & 63, l15 = lane & 15, quad = lane >> 4;
    const int mt = wv & 3, nt = wv >> 2;

    // ---- one-time init: weight slices -> LDS
    {
        int row = tid >> 4;
        int c0 = (tid & 15) * 32;
        int src_n = (row < 16) ? (16 * g + row) : (512 + 16 * g + (row - 16));
        const unsigned short* s = WgT + (size_t)src_n * 512 + c0;
        unsigned short* d = &Wgl[row][c0];
#pragma unroll
        for (int q = 0; q < 4; ++q) ((uint4*)d)[q] = ((const uint4*)s)[q];
    }
    if (tid < 256) {
        int row = tid >> 4;
        int c0 = (tid & 15) * 32;
        const unsigned short* s = WcT + (size_t)(16 * g + row) * 512 + c0;
        unsigned short* d = &Wcl[row][c0];
#pragma unroll
        for (int q = 0; q < 4; ++q) ((uint4*)d)[q] = ((const uint4*)s)[q];
    }
    if (tid < 32) fg_l[tid] = Wg[(size_t)512 * 1024 +
                                 ((tid < 16) ? (16 * g + tid) : (512 + 16 * g + tid - 16))];
    if (tid < 16) { fc_l[tid] = Wc[(size_t)512 * 512 + 16 * g + tid];
                    wh_l[tid] = whalt[16 * g + tid]; }
    for (int x = tid; x < 64 * 520; x += RTHREADS) ((unsigned short*)Hs)[x] = 0;
    if (tid < 64) { cum_s[tid] = 0; rem_s[tid] = 0; nupd_s[tid] = 0; pond_s[tid] = 0; }
    const float bh = bhalt[0];
    __syncthreads();

    unsigned int seq = 0;
    floatx4 accr = {0, 0, 0, 0};
    float hn[4] = {0, 0, 0, 0};

    for (int t = 0; t < TT; ++t) {
        // stage x-slices for this timestep into LDS (plain cached loads)
        {
            int row = tid >> 3, cc = (tid & 7) * 4;
            int gcol = (cc < 16) ? (16 * g + cc) : (512 + 16 * g + (cc - 16));
            *(u64*)&xg_l[row][cc] = *(const u64*)(Xg + (size_t)(t * 64 + row) * 1024 + gcol);
        }
        if (tid < 256) {
            int row = tid >> 2, c4 = (tid & 3) * 4;
            *(float4*)&xc_l[row][c4] = *(const float4*)(Xc + (size_t)(t * 64 + row) * 512 + 16 * g + c4);
        }
        __syncthreads();

        for (int i = 0; i < MAXC; ++i) {
            // ---- stage A: gates GEMM  C[64][32] = Hs @ Wg_slice
            floatx4 acg = {0, 0, 0, 0};
            const int arow = mt * 16 + l15;
            const int brow = nt * 16 + l15;
#pragma unroll
            for (int kk = 0; kk < 16; ++kk) {
                short8 a = *(const short8*)&Hs[arow][kk * 32 + quad * 8];
                short8 b = *(const short8*)&Wgl[brow][kk * 32 + quad * 8];
                acg = __builtin_amdgcn_mfma_f32_16x16x32_bf16(a, b, acg, 0, 0, 0);
            }
#pragma unroll
            for (int e = 0; e < 4; ++e) {
                int m = mt * 16 + quad * 4 + e;
                float pre = acg[e] + bf2f(xg_l[m][nt * 16 + l15])
                            + ((i == 0) ? fg_l[nt * 16 + l15] : 0.0f);
                float s = sigmoidf_(pre);
                if (nt == 0) rh_l[m][l15] = s * bf2f(Hs[m][16 * g + l15]);
                else         u_l[m][l15] = s;
            }
            __syncthreads();
            if (tid < 256) {   // pack rh slice -> RHX (8B coherent stores)
                int row = tid >> 2, q = tid & 3;
                u64 v = (u64)f2bf(rh_l[row][q * 4 + 0])
                      | ((u64)f2bf(rh_l[row][q * 4 + 1]) << 16)
                      | ((u64)f2bf(rh_l[row][q * 4 + 2]) << 32)
                      | ((u64)f2bf(rh_l[row][q * 4 + 3]) << 48);
                ast8(RHX + (size_t)row * 512 + 16 * g + q * 4, v);
            }
            xbar(flags, ++seq);             // rh slices complete device-wide

            // ---- stage B: cand GEMM  C2[64][16] = RH @ Wc_slice  (waves 0-3)
            if (wv < 4) {
                short8 af[16];
#pragma unroll
                for (int kk = 0; kk < 16; ++kk)
                    af[kk] = ald16(RHX + (size_t)(mt * 16 + l15) * 512 + kk * 32 + quad * 8);
                floatx4 ac2 = {0, 0, 0, 0};
#pragma unroll
                for (int kk = 0; kk < 16; ++kk) {
                    short8 b = *(const short8*)&Wcl[l15][kk * 32 + quad * 8];
                    ac2 = __builtin_amdgcn_mfma_f32_16x16x32_bf16(af[kk], b, ac2, 0, 0, 0);
                }
#pragma unroll
                for (int e = 0; e < 4; ++e) {
                    int m = mt * 16 + quad * 4 + e;
                    float pre = ac2[e] + xc_l[m][l15] + ((i == 0) ? fc_l[l15] : 0.0f);
                    float c = tanhf(pre);
                    float u = u_l[m][l15];
                    float h = bf2f(Hs[m][16 * g + l15]);
                    hn[e] = u * h + (1.0f - u) * c;
                    hn_l[m][l15] = hn[e];
                    pl[m][l15] = hn[e] * wh_l[l15];
                }
            }
            __syncthreads();
            if (tid < 256) {   // pack h_new slice -> HNX
                int row = tid >> 2, q = tid & 3;
                u64 v = (u64)f2bf(hn_l[row][q * 4 + 0])
                      | ((u64)f2bf(hn_l[row][q * 4 + 1]) << 16)
                      | ((u64)f2bf(hn_l[row][q * 4 + 2]) << 32)
                      | ((u64)f2bf(hn_l[row][q * 4 + 3]) << 48);
                ast8(HNX + (size_t)row * 512 + 16 * g + q * 4, v);
            }
            if (tid < 64) {
                float s = 0.0f;
#pragma unroll
                for (int j = 0; j < 16; ++j) s += pl[tid][j];
                __hip_atomic_store(Pp + g * 64 + tid, s, __ATOMIC_RELAXED,
                                   __HIP_MEMORY_SCOPE_AGENT);
            }
            xbar(flags, ++seq);             // h_new + halting partials complete

            // ---- stage C: ACT bookkeeping (redundant, bitwise-identical per block)
            if (tid < 64) {
                float logit = bh;
#pragma unroll
                for (int gg = 0; gg < GBLK; ++gg)
                    logit += __hip_atomic_load(Pp + gg * 64 + tid, __ATOMIC_RELAXED,
                                               __HIP_MEMORY_SCOPE_AGENT);
                float p = sigmoidf_(logit);
                float cum = cum_s[tid];
                bool still = cum < 0.99f;
                bool halts = still && ((cum + p >= 0.99f) || (i == MAXC - 1));
                w_s[tid] = still ? (halts ? (1.0f - cum) : p) : 0.0f;
                still_s[tid] = still ? 1 : 0;
                if (halts) rem_s[tid] = 1.0f - cum;
                if (still) { nupd_s[tid] += 1.0f; cum_s[tid] = cum + p; }
                unsigned long long act = __ballot(still && !halts);
                if (tid == 0) allh_s = (act == 0ull) ? 1 : 0;
            }
            __syncthreads();
            if (wv < 4) {
#pragma unroll
                for (int e = 0; e < 4; ++e) {
                    int m = mt * 16 + quad * 4 + e;
                    accr[e] += w_s[m] * hn[e];
                }
            }
            {   // Hs := still ? h_new : Hs  (coherent loads, 128 B/thread)
                int row = tid >> 3, c0s = (tid & 7) * 64;
                if (still_s[row]) {
                    const unsigned short* s = HNX + (size_t)row * 512 + c0s;
#pragma unroll
                    for (int q = 0; q < 16; ++q)
                        *(u64*)&Hs[row][c0s + q * 4] = ald8(s + q * 4);
                }
            }
            __syncthreads();
            if (allh_s) break;              // uniform across blocks
        }

        // ---- timestep epilogue: output = acc; NEXT-STEP STATE = acc
        if (wv < 4) {
#pragma unroll
            for (int e = 0; e < 4; ++e) {
                int m = mt * 16 + quad * 4 + e;
                int j = 16 * g + l15;
                unsigned short ab = f2bf(accr[e]);
                outsb[(size_t)(m * TT + t) * 512 + j] = ab;   // plain store (next kernel)
                rh_l[m][l15] = accr[e];
                accr[e] = 0.0f;
            }
        }
        __syncthreads();
        if (tid < 256) {       // pack acc slice -> AccX
            int row = tid >> 2, q = tid & 3;
            u64 v = (u64)f2bf(rh_l[row][q * 4 + 0])
                  | ((u64)f2bf(rh_l[row][q * 4 + 1]) << 16)
                  | ((u64)f2bf(rh_l[row][q * 4 + 2]) << 32)
                  | ((u64)f2bf(rh_l[row][q * 4 + 3]) << 48);
            ast8(AccX + (size_t)row * 512 + 16 * g + q * 4, v);
        }
        if (tid < 64) {
            pond_s[tid] += nupd_s[tid] + rem_s[tid];
            cum_s[tid] = 0; rem_s[tid] = 0; nupd_s[tid] = 0;
        }
        xbar(flags, ++seq);                 // acc slices complete device-wide
        {
            int row = tid >> 3, c0s = (tid & 7) * 64;
            const unsigned short* s = AccX + (size_t)row * 512 + c0s;
#pragma unroll
            for (int q = 0; q < 16; ++q)
                *(u64*)&Hs[row][c0s + q * 4] = ald8(s + q * 4);
        }
        __syncthreads();
    }
    if (g == 0 && tid < 64) ponder_b[tid] = pond_s[tid];
}

// ---------------------------------------------------------------------------
// Kernel 3a: fp32 -> bf16 convert (softmax_w)
// ---------------------------------------------------------------------------
__global__ __launch_bounds__(256) void cvt_bf16(
    const float* __restrict__ s, unsigned short* __restrict__ d)
{
    int i = (blockIdx.x * 256 + threadIdx.x) * 4;
    float4 v = *(const float4*)(s + i);
    u64 p = (u64)f2bf(v.x) | ((u64)f2bf(v.y) << 16)
          | ((u64)f2bf(v.z) << 32) | ((u64)f2bf(v.w) << 48);
    *(u64*)(d + i) = p;
}

// ---------------------------------------------------------------------------
// Kernel 3b: logits = outs @ softmax_w^T + softmax_b, bf16 MFMA, 128x64 tiles.
// ---------------------------------------------------------------------------
__global__ __launch_bounds__(256) void logits_mfma(
    const unsigned short* __restrict__ A,   // [8192][512] bf16
    const unsigned short* __restrict__ Bw,  // [8000][512] bf16
    const float* __restrict__ sb, float* __restrict__ out)
{
    __shared__ unsigned short As[128][40];
    __shared__ unsigned short Bs[64][40];
    const int n0 = blockIdx.x * 64, m0 = blockIdx.y * 128;
    const int tid = threadIdx.x;
    const int wv = tid >> 6, lane = tid & 63, l15 = lane & 15, quad = lane >> 4;

    floatx4 acc[2][4] = {};
    for (int k0 = 0; k0 < HH; k0 += 32) {
#pragma unroll
        for (int c = tid; c < 512; c += 256) {
            int r = c >> 2, q = c & 3;
            *(uint4*)&As[r][q * 8] = *(const uint4*)(A + (size_t)(m0 + r) * 512 + k0 + q * 8);
        }
        {
            int n = tid >> 2, q = tid & 3;
            *(uint4*)&Bs[n][q * 8] = *(const uint4*)(Bw + (size_t)(n0 + n) * 512 + k0 + q * 8);
        }
        __syncthreads();
        short8 b[4];
#pragma unroll
        for (int nb = 0; nb < 4; ++nb) b[nb] = *(const short8*)&Bs[nb * 16 + l15][quad * 8];
#pragma unroll
        for (int r = 0; r < 2; ++r) {
            short8 a = *(const short8*)&As[wv * 32 + r * 16 + l15][quad * 8];
#pragma unroll
            for (int nb = 0; nb < 4; ++nb)
                acc[r][nb] = __builtin_amdgcn_mfma_f32_16x16x32_bf16(a, b[nb], acc[r][nb], 0, 0, 0);
        }
        __syncthreads();
    }
#pragma unroll
    for (int r = 0; r < 2; ++r)
#pragma unroll
        for (int nb = 0; nb < 4; ++nb)
#pragma unroll
            for (int e = 0; e < 4; ++e) {
                int row = m0 + wv * 32 + r * 16 + quad * 4 + e;
                int col = n0 + nb * 16 + l15;
                out[(size_t)row * VV + col] = acc[r][nb][e] + sb[col];
            }
}

// ---------------------------------------------------------------------------
// Kernel 4: ponder cost = 0.01 * mean_b(ponder_b)
// ---------------------------------------------------------------------------
__global__ void ponder_kernel(const float* __restrict__ pb, float* __restrict__ out,
                              unsigned long long off)
{
    const int lane = threadIdx.x;
    float v = pb[lane];
#pragma unroll
    for (int o = 32; o > 0; o >>= 1) v += __shfl_down(v, o, 64);
    if (lane == 0) out[off] = 0.01f * (v * (1.0f / 64.0f));
}

// ---------------------------------------------------------------------------
extern "C" void kernel_launch(void* const* d_in, const int* in_sizes, int n_in,
                              void* d_out, int out_size, void* d_ws, size_t ws_size,
                              hipStream_t stream)
{
    const int*   idx = (const int*)d_in[0];
    const float* emb = (const float*)d_in[1];
    const float* Wg  = (const float*)d_in[2];
    const float* bg  = (const float*)d_in[3];
    const float* Wc  = (const float*)d_in[4];
    const float* bc  = (const float*)d_in[5];
    const float* wh  = (const float*)d_in[6];
    const float* bh  = (const float*)d_in[7];
    const float* sw  = (const float*)d_in[8];
    const float* sb  = (const float*)d_in[9];
    float* out = (float*)d_out;

    char* p = (char*)d_ws;
    unsigned int* flags = (unsigned int*)p;      p += 256;
    float* Xc  = (float*)p;                      p += (size_t)8192 * 512 * 4;
    float* pb  = (float*)p;                      p += 256;
    float* Pp  = (float*)p;                      p += (size_t)GBLK * 64 * 4;
    unsigned short* Xg    = (unsigned short*)p;  p += (size_t)8192 * 1024 * 2;
    unsigned short* WgT   = (unsigned short*)p;  p += (size_t)1024 * 512 * 2;
    unsigned short* WcT   = (unsigned short*)p;  p += (size_t)512 * 512 * 2;
    unsigned short* RHX   = (unsigned short*)p;  p += (size_t)64 * 512 * 2;
    unsigned short* HNX   = (unsigned short*)p;  p += (size_t)64 * 512 * 2;
    unsigned short* AccX  = (unsigned short*)p;  p += (size_t)64 * 512 * 2;
    unsigned short* outsb = (unsigned short*)p;  p += (size_t)8192 * 512 * 2;
    unsigned short* swb   = (unsigned short*)p;  p += (size_t)VV * 512 * 2;

    hipMemsetAsync(flags, 0, 256, stream);
    transpose_w<<<192, 256, 0, stream>>>(Wg, Wc, WgT, WcT);
    xproj_kernel<<<dim3(16, 128), 256, 0, stream>>>(idx, emb, Wg, bg, nullptr, Xg, 1024);
    xproj_kernel<<<dim3(8, 128), 256, 0, stream>>>(idx, emb, Wc, bc, Xc, nullptr, 512);
    cvt_bf16<<<(VV * 512) / 1024, 256, 0, stream>>>(sw, swb);
    act_rnn_batched<<<GBLK, RTHREADS, 0, stream>>>(WgT, WcT, Wg, Wc, wh, bh, Xg, Xc,
                                                   outsb, pb, RHX, HNX, AccX, Pp, flags);
    logits_mfma<<<dim3(VV / 64, 64), 256, 0, stream>>>(outsb, swb, sb, out);
    ponder_kernel<<<1, 64, 0, stream>>>(pb, out, (unsigned long long)8192 * VV);
}